// Round 13
// baseline (2491.439 us; speedup 1.0000x reference)
//
#include <hip/hip_runtime.h>
#include <stdint.h>

// PoseRNN: fused = cat(fv,fi) -> 2-layer GRU(768) -> Linear(768,128)+LeakyReLU(0.1) -> Linear(128,6)
// Persistent pipelined 2-layer GRU. 96 WGs = 2 layers x 48 slices; 512 threads (8 waves):
// waves 0-3 x-GEMM+combine (16 batch rows each), waves 4-7 h-GEMM.
// Round-13: attack the per-round handshake (R9-R12 all ~9us/round regardless of structure):
//   1. store packing: combine stages f32 hn2 into ghbuf's already-consumed col 0..15 region
//      (same-lane read-then-write; LDS in-order per wave), then an in-wave transpose read
//      (f32x4 per lane) -> ONE 8B relaxed-agent store per lane (was 4 scattered dwords).
//   2. no sync2: flag released by the LAST x-wave via LDS fetch_add, each wave adds only
//      after draining its own stores -> flag implies all 4 waves' h-stores ACKed at L3.
//      ghbuf WAR is protected by the flag chain itself (gh can't write round i+1 before
//      own-WG flag i, which is after x-waves consumed ghbuf i).
//   3. single far-poller per dependency (wave4: h-flags; wave0 layer1: x-flags) + round-
//      tagged LDS broadcast for the other waves -> ~4x less far-poll fabric traffic.
// Visibility protocol unchanged (proven R7+): relaxed-agent write-through h stores,
// relaxed-agent L2-bypassing polls, zero fences, zero cache maintenance in the loop.

typedef __attribute__((ext_vector_type(8))) short bf16x8;   // 8 bf16 in 4 VGPRs
typedef __attribute__((ext_vector_type(4))) short bf16x4;   // 8B
typedef __attribute__((ext_vector_type(4))) float f32x4;

#define H_   768
#define TH3  2304
#define BATCH 64
#define SEQ  256
#define SLAB (BATCH * H_)   /* 49152 elems, one timestep of h/y for all batches */
#define WROW 772            /* padded LDS row stride (ushorts) */
#define FL_STRIDE 128       /* ints per round: layer0 at +0, layer1 at +64 (48 used each) */

__device__ __forceinline__ uint16_t f2b(float f) {
  union { float f; uint32_t u; } v; v.f = f;
  uint32_t u = v.u;
  return (uint16_t)((u + 0x7FFFu + ((u >> 16) & 1u)) >> 16);  // RNE
}

__device__ __forceinline__ f32x4 mfma16(bf16x8 a, bf16x8 b, f32x4 c) {
  return __builtin_amdgcn_mfma_f32_16x16x32_bf16(a, b, c, 0, 0, 0);
}

__device__ __forceinline__ bf16x8 ldB(const uint16_t* p) {   // two ds_read_b64 (8B-aligned rows)
  bf16x4 lo = *reinterpret_cast<const bf16x4*>(p);
  bf16x4 hi = *reinterpret_cast<const bf16x4*>(p + 4);
  bf16x8 r;
  r[0] = lo[0]; r[1] = lo[1]; r[2] = lo[2]; r[3] = lo[3];
  r[4] = hi[0]; r[5] = hi[1]; r[6] = hi[2]; r[7] = hi[3];
  return r;
}

__device__ __forceinline__ void pollFlags48(const int* base, int lane) {
  const int* fp = base + (lane < 48 ? lane : 0);
  int spins = 0;
  for (;;) {
    int v = __hip_atomic_load(fp, __ATOMIC_RELAXED, __HIP_MEMORY_SCOPE_AGENT);
    if (lane >= 48) v = 1;
    if (__all(v != 0)) break;
    if (++spins > (1 << 16)) break;  // hang guard; break => absmax fail, not timeout
    __builtin_amdgcn_s_sleep(1);
  }
  __builtin_amdgcn_sched_barrier(0);  // nothing (esp. A-loads) may hoist above the poll
}

__device__ __forceinline__ void ldsSpin(int* addr, int want) {
  int spins = 0;
  while (__hip_atomic_load(addr, __ATOMIC_RELAXED, __HIP_MEMORY_SCOPE_WORKGROUP) != want) {
    if (++spins > (1 << 20)) break;  // hang guard
  }
  __builtin_amdgcn_sched_barrier(0);
}

__device__ __forceinline__ float fsig(float x) {
  return 1.0f / (1.0f + __expf(-x));
}
__device__ __forceinline__ float ftanh(float x) {
  x = fminf(fmaxf(x, -15.0f), 15.0f);
  float e = __expf(2.0f * x);
  return (e - 1.0f) / (e + 1.0f);
}

// ---------------- prep: build time-major bf16 X, zero flags, bf16 W1 -------------
__global__ __launch_bounds__(256) void prep_kernel(
    const float* __restrict__ fv, const float* __restrict__ fi,
    const float* __restrict__ W1,
    uint16_t* __restrict__ Xbf, int* __restrict__ flags, uint16_t* __restrict__ W1b)
{
  const int NX = SEQ * SLAB;          // 12,582,912
  const int NC = 257 * FL_STRIDE;     // 32,896 flag ints
  const int NW = 128 * H_;
  const int total = NX + NC + NW;
  for (int idx = blockIdx.x * blockDim.x + threadIdx.x; idx < total;
       idx += gridDim.x * blockDim.x) {
    if (idx < NX) {
      int s = idx / SLAB;
      int rem = idx - s * SLAB;
      int b = rem / H_;
      int h = rem - b * H_;
      float val = (h < 512) ? fv[((size_t)b * SEQ + s) * 512 + h]
                            : fi[((size_t)b * SEQ + s) * 256 + (h - 512)];
      Xbf[idx] = f2b(val);
    } else if (idx < NX + NC) {
      flags[idx - NX] = 0;
    } else {
      int k = idx - NX - NC;
      W1b[k] = f2b(W1[k]);
    }
  }
}

// ---------------- persistent pipelined 2-layer GRU: 96 WGs x 512 threads ----------------
__global__ __launch_bounds__(512) void gru_persist(
    const float* __restrict__ Wih, const float* __restrict__ Whh,
    const float* __restrict__ bih, const float* __restrict__ bhh,
    const uint16_t* __restrict__ Xbf, uint16_t* __restrict__ Y0, uint16_t* __restrict__ Y1,
    int* __restrict__ flags, float* __restrict__ out_hn)
{
  __shared__ __attribute__((aligned(16))) uint16_t Wx[48 * WROW];  // 74,112 B
  __shared__ __attribute__((aligned(16))) uint16_t Wh[48 * WROW];  // 74,112 B
  __shared__ __attribute__((aligned(16))) float ghbuf[64 * 48];    // 12,288 B
  __shared__ float bI[48];
  __shared__ float bH[48];
  __shared__ int ready_h, ready_x, wcnt;                           // total ~160.9 KB

  const int bid   = blockIdx.x;        // 0..95
  const int slice = bid % 48;          // hidden slice: units [slice*16, slice*16+16)
  const int layer = bid / 48;          // 0 or 1
  const int tid  = threadIdx.x;
  const int lane = tid & 63;
  const int wid  = tid >> 6;           // 8 waves
  const int isGh = wid >> 2;           // waves 0-3: x-GEMM+combine; waves 4-7: h-GEMM
  const int mblk = wid & 3;            // 16-batch block (0..3)
  const int n16  = lane & 15;
  const int kg   = lane >> 4;

  if (tid == 0) { ready_h = -1; ready_x = -1; wcnt = 0; }

  // --- one-time: weight slices -> LDS bf16; rows ordered [r(16) z(16) n(16)] ---
  const float* wx_g = Wih + (size_t)layer * TH3 * H_;
  const float* wh_g = Whh + (size_t)layer * TH3 * H_;
  for (int idx = tid; idx < 48 * H_; idx += 512) {
    int lr = idx / H_;
    int c  = idx - lr * H_;
    int gate = lr >> 4, j = lr & 15;
    size_t grow = (size_t)(gate * H_ + slice * 16 + j);
    Wx[lr * WROW + c] = f2b(wx_g[grow * H_ + c]);
    Wh[lr * WROW + c] = f2b(wh_g[grow * H_ + c]);
  }
  if (tid < 48) {
    int gate = tid >> 4, j = tid & 15;
    bI[tid] = bih[layer * TH3 + gate * H_ + slice * 16 + j];
    bH[tid] = bhh[layer * TH3 + gate * H_ + slice * 16 + j];
  }
  __syncthreads();

  uint16_t* Yown = layer ? Y1 : Y0;
  const uint16_t* Wh_base = Wh + (size_t)n16 * WROW + kg * 8;
  const uint16_t* Wx_base = Wx + (size_t)n16 * WROW + kg * 8;

  f32x4 xac0 = {0,0,0,0}, xac1 = {0,0,0,0}, xac2 = {0,0,0,0};  // x-wave acc
  float hp[4] = {0.0f, 0.0f, 0.0f, 0.0f};                      // running h (x-waves)

  for (int i = 0; i <= 256; ++i) {
    const bool active = (layer == 0) ? (i < 256) : (i >= 1);
    const bool firstA = (layer == 0) ? (i == 0) : (i == 1);

    // ================= phase 1: GEMMs =================
    if (active) {
      if (isGh) {
        if (firstA) {
          // h0 == 0 -> gh == 0; no poll, no GEMM
          #pragma unroll
          for (int q = 0; q < 4; ++q) {
            int bi = mblk * 16 + 4 * kg + q;
            ghbuf[bi * 48 +      n16] = 0.0f;
            ghbuf[bi * 48 + 16 + n16] = 0.0f;
            ghbuf[bi * 48 + 32 + n16] = 0.0f;
          }
        } else {
          // h producers = own layer's 48 slices, round i-1. Wave 4 far-polls, broadcasts.
          if (wid == 4) {
            pollFlags48(flags + (size_t)(i - 1) * FL_STRIDE + layer * 64, lane);
            if (lane == 0)
              __hip_atomic_store(&ready_h, i, __ATOMIC_RELAXED, __HIP_MEMORY_SCOPE_WORKGROUP);
          } else {
            ldsSpin(&ready_h, i);
          }
          const uint16_t* hs = (layer == 0) ? (Y0 + (size_t)i * SLAB)
                                            : (Y1 + (size_t)(i - 1) * SLAB);
          const uint16_t* ap = hs + (size_t)(mblk * 16 + n16) * H_ + kg * 8;
          f32x4 a0 = {0,0,0,0}, a1 = {0,0,0,0}, a2 = {0,0,0,0};
          #pragma unroll
          for (int ks = 0; ks < 24; ++ks) {
            bf16x8 av  = *reinterpret_cast<const bf16x8*>(ap + ks * 32);
            bf16x8 bv0 = ldB(Wh_base + ks * 32);
            bf16x8 bv1 = ldB(Wh_base + 16 * WROW + ks * 32);
            bf16x8 bv2 = ldB(Wh_base + 32 * WROW + ks * 32);
            a0 = mfma16(av, bv0, a0);
            a1 = mfma16(av, bv1, a1);
            a2 = mfma16(av, bv2, a2);
          }
          #pragma unroll
          for (int q = 0; q < 4; ++q) {
            int bi = mblk * 16 + 4 * kg + q;          // D row = 4*(lane>>4)+q
            ghbuf[bi * 48 +      n16] = a0[q];
            ghbuf[bi * 48 + 16 + n16] = a1[q];
            ghbuf[bi * 48 + 32 + n16] = a2[q];
          }
        }
      } else {
        // x input: layer0 reads Xbf[i] (static, no poll); layer1 reads Y0[i] (layer0 rnd i-1).
        if (layer == 1) {
          if (wid == 0) {
            pollFlags48(flags + (size_t)(i - 1) * FL_STRIDE, lane);
            if (lane == 0)
              __hip_atomic_store(&ready_x, i, __ATOMIC_RELAXED, __HIP_MEMORY_SCOPE_WORKGROUP);
          } else {
            ldsSpin(&ready_x, i);
          }
        }
        const uint16_t* xs = (layer == 0) ? (Xbf + (size_t)i * SLAB)
                                          : (Y0 + (size_t)i * SLAB);
        const uint16_t* ap = xs + (size_t)(mblk * 16 + n16) * H_ + kg * 8;
        f32x4 a0 = {0,0,0,0}, a1 = {0,0,0,0}, a2 = {0,0,0,0};
        #pragma unroll
        for (int ks = 0; ks < 24; ++ks) {
          bf16x8 av  = *reinterpret_cast<const bf16x8*>(ap + ks * 32);
          bf16x8 bv0 = ldB(Wx_base + ks * 32);
          bf16x8 bv1 = ldB(Wx_base + 16 * WROW + ks * 32);
          bf16x8 bv2 = ldB(Wx_base + 32 * WROW + ks * 32);
          a0 = mfma16(av, bv0, a0);
          a1 = mfma16(av, bv1, a1);
          a2 = mfma16(av, bv2, a2);
        }
        xac0 = a0; xac1 = a1; xac2 = a2;
      }
    }
    __syncthreads();  // single barrier per round: ghbuf + xacc ready

    // ================= phase 2: combine + store (x waves), no second barrier =================
    if (active && !isGh) {
      uint16_t* dst = Yown + (size_t)((layer == 0) ? (i + 1) : i) * SLAB;
      const bool lastStep = (layer == 0) ? (i == 255) : (i == 256);
      #pragma unroll
      for (int q = 0; q < 4; ++q) {
        int bi = mblk * 16 + 4 * kg + q;
        float ghr = ghbuf[bi * 48 +      n16] + bH[n16];
        float ghz = ghbuf[bi * 48 + 16 + n16] + bH[16 + n16];
        float ghn = ghbuf[bi * 48 + 32 + n16] + bH[32 + n16];
        float gxr = xac0[q] + bI[n16];
        float gxz = xac1[q] + bI[16 + n16];
        float gxn = xac2[q] + bI[32 + n16];
        float rg = fsig(gxr + ghr);
        float zg = fsig(gxz + ghz);
        float ng = ftanh(gxn + rg * ghn);
        float hn2 = (1.0f - zg) * ng + zg * hp[q];
        hp[q] = hn2;
        // stage f32 result into the just-consumed gate-r slot (same lane, same address)
        ghbuf[bi * 48 + n16] = hn2;
      }
      __builtin_amdgcn_sched_barrier(0);  // LDS writes above stay above the transpose read

      // in-wave transpose: lane -> (row within mblk, 4-col group); one 8B store per lane
      {
        int row16 = lane & 15;
        int cg    = lane >> 4;            // 0..3, 4 cols each
        int row   = mblk * 16 + row16;
        f32x4 v = *reinterpret_cast<const f32x4*>(&ghbuf[row * 48 + cg * 4]);
        uint64_t u = (uint64_t)f2b(v[0])
                   | ((uint64_t)f2b(v[1]) << 16)
                   | ((uint64_t)f2b(v[2]) << 32)
                   | ((uint64_t)f2b(v[3]) << 48);
        unsigned long long* p =
            (unsigned long long*)(dst + (size_t)row * H_ + slice * 16 + cg * 4);
        __hip_atomic_store(p, u, __ATOMIC_RELAXED, __HIP_MEMORY_SCOPE_AGENT);
        if (lastStep)
          *reinterpret_cast<f32x4*>(
              &out_hn[(size_t)layer * SLAB + (size_t)row * H_ + slice * 16 + cg * 4]) = v;
      }
      __builtin_amdgcn_s_waitcnt(0);      // drain THIS wave's h-stores
      __builtin_amdgcn_sched_barrier(0);  // arrive must not move above the drain
      if (lane == 0) {
        int ret = __hip_atomic_fetch_add(&wcnt, 1, __ATOMIC_RELAXED,
                                         __HIP_MEMORY_SCOPE_WORKGROUP);
        int nprev = (layer == 0) ? i : (i - 1);   // rounds completed by this WG before now
        if (ret == nprev * 4 + 3)                 // last x-wave: all 4 waves' stores ACKed
          __hip_atomic_store(&flags[(size_t)i * FL_STRIDE + layer * 64 + slice], 1,
                             __ATOMIC_RELAXED, __HIP_MEMORY_SCOPE_AGENT);
      }
    }
  }
}

// ---------------- regressor: pose = LeakyReLU(Y1 @ W1^T + b1) @ W2^T + b2 ----------------
__global__ __launch_bounds__(256) void regressor_kernel(
    const uint16_t* __restrict__ Y1, const uint16_t* __restrict__ W1b,
    const float* __restrict__ b1, const float* __restrict__ W2,
    const float* __restrict__ b2, float* __restrict__ pose)
{
  __shared__ float hdn[64 * 132];
  const int t = blockIdx.x;      // timestep
  const int tid = threadIdx.x;
  const int lane = tid & 63;
  const int wid = tid >> 6;
  const int n16 = lane & 15;
  const int kg = lane >> 4;

  const uint16_t* A  = Y1 + (size_t)(t + 1) * SLAB + (size_t)(wid * 16) * H_;
  const uint16_t* ap = A + (size_t)n16 * H_ + kg * 8;
  const uint16_t* bp = W1b + (size_t)n16 * H_ + kg * 8;

  f32x4 acc[8];
  #pragma unroll
  for (int i = 0; i < 8; ++i) acc[i] = (f32x4){0,0,0,0};

  #pragma unroll
  for (int ks = 0; ks < 24; ++ks) {
    bf16x8 av = *reinterpret_cast<const bf16x8*>(ap + ks * 32);
    #pragma unroll
    for (int nt = 0; nt < 8; ++nt) {
      bf16x8 bv = *reinterpret_cast<const bf16x8*>(bp + (size_t)nt * 16 * H_ + ks * 32);
      acc[nt] = mfma16(av, bv, acc[nt]);
    }
  }
  #pragma unroll
  for (int nt = 0; nt < 8; ++nt) {
    #pragma unroll
    for (int q = 0; q < 4; ++q) {
      int brow = wid * 16 + 4 * kg + q;
      int col  = nt * 16 + n16;
      float v = acc[nt][q] + b1[col];
      v = (v >= 0.0f) ? v : 0.1f * v;   // LeakyReLU(0.1)
      hdn[brow * 132 + col] = v;
    }
  }
  __syncthreads();
  for (int idx = tid; idx < 384; idx += 256) {
    int b = idx / 6, o = idx % 6;
    const float* w2r = W2 + o * 128;
    const float* hr  = &hdn[b * 132];
    float s = b2[o];
    #pragma unroll 4
    for (int c = 0; c < 128; ++c) s += hr[c] * w2r[c];
    pose[(size_t)b * (SEQ * 6) + (size_t)t * 6 + o] = s;
  }
}

extern "C" void kernel_launch(void* const* d_in, const int* in_sizes, int n_in,
                              void* d_out, int out_size, void* d_ws, size_t ws_size,
                              hipStream_t stream) {
  const float* fv  = (const float*)d_in[0];
  const float* fi  = (const float*)d_in[1];
  // d_in[2] = ts (unused by the reference)
  const float* Wih = (const float*)d_in[3];
  const float* Whh = (const float*)d_in[4];
  const float* bih = (const float*)d_in[5];
  const float* bhh = (const float*)d_in[6];
  const float* W1  = (const float*)d_in[7];
  const float* b1  = (const float*)d_in[8];
  const float* W2  = (const float*)d_in[9];
  const float* b2  = (const float*)d_in[10];
  float* out = (float*)d_out;   // [pose: 64*256*6][h_n: 2*64*768]

  char* ws = (char*)d_ws;
  size_t off = 0;
  int* flags = (int*)(ws + off);
  off += (size_t)257 * FL_STRIDE * sizeof(int);   // 131.6 KB
  off = (off + 255) & ~(size_t)255;
  uint16_t* Xbf = (uint16_t*)(ws + off); off += (size_t)SEQ * SLAB * 2;   // 25.2 MB
  uint16_t* Y0  = (uint16_t*)(ws + off); off += (size_t)257 * SLAB * 2;   // 25.3 MB
  uint16_t* Y1  = (uint16_t*)(ws + off); off += (size_t)257 * SLAB * 2;   // 25.3 MB
  uint16_t* W1b = (uint16_t*)(ws + off); off += (size_t)128 * H_ * 2;

  prep_kernel<<<2048, 256, 0, stream>>>(fv, fi, W1, Xbf, flags, W1b);
  gru_persist<<<96, 512, 0, stream>>>(Wih, Whh, bih, bhh, Xbf, Y0, Y1, flags, out + 98304);
  regressor_kernel<<<SEQ, 256, 0, stream>>>(Y1, W1b, b1, W2, b2, out);
}